// Round 5
// baseline (27510.303 us; speedup 1.0000x reference)
//
#include <hip/hip_runtime.h>
#include <math.h>

#define HWD 1089
#define WD 33
#define NF 128
#define NJ 124
#define CC 32

__device__ __forceinline__ float sigm(float z) { return 1.f / (1.f + expf(-z)); }
__device__ __forceinline__ int sel4(int4 v, int i) { return i == 0 ? v.x : i == 1 ? v.y : i == 2 ? v.z : v.w; }

// ---------------- rs[j] = sum_k mlp_w[j][k] ----------------
__global__ void rowsum_k(const float* __restrict__ mw, float* __restrict__ rs) {
    int j = blockIdx.x;
    const float* row = mw + (size_t)j * HWD;
    float s = 0.f;
    for (int k = threadIdx.x; k < HWD; k += 256) s += row[k];
    __shared__ float red[256];
    red[threadIdx.x] = s; __syncthreads();
    for (int off = 128; off > 0; off >>= 1) {
        if (threadIdx.x < off) red[threadIdx.x] += red[threadIdx.x + off];
        __syncthreads();
    }
    if (threadIdx.x == 0) rs[j] = red[0];
}

// ---------------- imgs = x * sigmoid((t/20)*rs + mlp_b) ----------------
__global__ void imgs_k(const float* __restrict__ x, const float* __restrict__ rs,
                       const float* __restrict__ mb, float* __restrict__ imgs) {
    int idx = blockIdx.x * 256 + threadIdx.x;
    if (idx >= NF * HWD) return;
    int t = idx / HWD, p = idx % HWD;
    float pe = sigm(((float)t / 20.0f) * rs[p] + mb[p]);
    imgs[idx] = x[idx] * pe;
}

// ---------------- 3x3 conv NHWC, PX pixels per thread ----------------
template <int CIN, int COUT, int PX, bool RELU, bool HAS_B, bool HAS_RES>
__global__ __launch_bounds__(256, 2)
void conv3x3_nhwc(const float* __restrict__ in,
                  const float* __restrict__ w, const float* __restrict__ b,
                  const float* __restrict__ res, int res_ps, int res_ns,
                  float* __restrict__ out, int out_ps, int out_ns, int Npix) {
    constexpr int WROW = (COUT + 3) & ~3;
    __shared__ float wl[9 * CIN * WROW];
    for (int i = threadIdx.x; i < 9 * CIN * WROW; i += 256) {
        int o = i % WROW, r = i / WROW;
        int c = r % CIN, k = r / CIN;
        wl[i] = (o < COUT) ? w[(o * CIN + c) * 9 + k] : 0.f;
    }
    __syncthreads();
    int base = (blockIdx.x * 256 + threadIdx.x) * PX;
    if (base >= Npix) return;
    // per-pixel geometry
    const float* ip0[PX];
    int h4[PX], q4[PX];
    bool alive[PX];
#pragma unroll
    for (int px = 0; px < PX; ++px) {
        int gid = base + px;
        alive[px] = gid < Npix;
        int g = alive[px] ? gid : base;
        int n = g / HWD, p = g - n * HWD;
        h4[px] = p / WD; q4[px] = p - h4[px] * WD;
        ip0[px] = in + (size_t)n * HWD * CIN + (size_t)p * CIN;
    }
    float acc[PX][COUT];
#pragma unroll
    for (int px = 0; px < PX; ++px)
#pragma unroll
        for (int o = 0; o < COUT; ++o) acc[px][o] = HAS_B ? b[o] : 0.f;
#pragma unroll
    for (int k = 0; k < 9; ++k) {
        int dy = k / 3 - 1, dx = k % 3 - 1;
        const float* ip[PX];
        bool v[PX];
#pragma unroll
        for (int px = 0; px < PX; ++px) {
            int hh = h4[px] + dy, qq = q4[px] + dx;
            v[px] = (hh >= 0 && hh < WD && qq >= 0 && qq < WD);
            ip[px] = ip0[px] + (dy * WD + dx) * CIN;
        }
        const float* wk = &wl[k * CIN * WROW];
#pragma unroll
        for (int cg = 0; cg < CIN / 4; ++cg) {
            float4 val[PX];
#pragma unroll
            for (int px = 0; px < PX; ++px)
                val[px] = v[px] ? *(const float4*)(ip[px] + cg * 4)
                                : make_float4(0.f, 0.f, 0.f, 0.f);
            const float* w0 = wk + (cg * 4) * WROW;
#pragma unroll
            for (int px = 0; px < PX; ++px)
#pragma unroll
                for (int o = 0; o < COUT; ++o)
                    acc[px][o] += val[px].x * w0[o] + val[px].y * w0[WROW + o]
                                + val[px].z * w0[2 * WROW + o] + val[px].w * w0[3 * WROW + o];
        }
    }
#pragma unroll
    for (int px = 0; px < PX; ++px) {
        if (!alive[px]) continue;
        int gid = base + px;
        int n = gid / HWD, p = gid - n * HWD;
#pragma unroll
        for (int o = 0; o < COUT; ++o) {
            float valv = acc[px][o];
            if (RELU) valv = fmaxf(valv, 0.f);
            if (HAS_RES) valv += res[(size_t)n * res_ns + (size_t)p * res_ps + o];
            out[(size_t)n * out_ns + (size_t)p * out_ps + o] = valv;
        }
    }
}

// ---------------- 3x3 conv, CHW input (fe 1->32, tc0 5->32), NHWC out ----------------
template <int CIN, int COUT, bool RELU>
__global__ __launch_bounds__(256, 2)
void conv3x3_chwin(const float* __restrict__ in, int in_ns,
                   const float* __restrict__ w, const float* __restrict__ b,
                   float* __restrict__ out, int N) {
    __shared__ float wl[CIN * 9 * COUT];
    for (int i = threadIdx.x; i < CIN * 9 * COUT; i += 256) {
        int o = i % COUT, r = i / COUT;
        int k = r % 9, c = r / 9;
        wl[i] = w[(o * CIN + c) * 9 + k];
    }
    __syncthreads();
    int idx = blockIdx.x * 256 + threadIdx.x;
    if (idx >= N * HWD) return;
    int n = idx / HWD, p = idx % HWD;
    int h = p / WD, q = p % WD;
    float acc[COUT];
#pragma unroll
    for (int o = 0; o < COUT; ++o) acc[o] = b[o];
    const float* inn = in + (size_t)n * in_ns;
#pragma unroll
    for (int c = 0; c < CIN; ++c) {
#pragma unroll
        for (int k = 0; k < 9; ++k) {
            int hh = h + k / 3 - 1, qq = q + k % 3 - 1;
            if (hh < 0 || hh >= WD || qq < 0 || qq >= WD) continue;
            float v = inn[c * HWD + hh * WD + qq];
            const float* wp = &wl[(c * 9 + k) * COUT];
#pragma unroll
            for (int o = 0; o < COUT; ++o) acc[o] += v * wp[o];
        }
    }
    float* op = out + ((size_t)idx) * COUT;
#pragma unroll
    for (int o = 0; o < COUT; ++o) op[o] = RELU ? fmaxf(acc[o], 0.f) : acc[o];
}

// ---------------- a1c = 1x1 conv (16 out) of feats[n+2], NHWC ----------------
__global__ void a1c_k(const float* __restrict__ feats, const float* __restrict__ w,
                      const float* __restrict__ b, float* __restrict__ a1c) {
    __shared__ float wl[CC * 16];
    for (int i = threadIdx.x; i < CC * 16; i += 256) {
        int o = i % 16, c = i / 16;
        wl[i] = w[o * CC + c];
    }
    __syncthreads();
    int idx = blockIdx.x * 256 + threadIdx.x;
    if (idx >= NJ * HWD) return;
    int n = idx / HWD, p = idx % HWD;
    const float* f = feats + ((size_t)(n + 2) * HWD + p) * CC;
    float acc[16];
#pragma unroll
    for (int o = 0; o < 16; ++o) acc[o] = b[o];
#pragma unroll
    for (int cg = 0; cg < 8; ++cg) {
        float4 v = *(const float4*)(f + cg * 4);
        const float* w0 = &wl[cg * 4 * 16];
#pragma unroll
        for (int o = 0; o < 16; ++o)
            acc[o] += v.x * w0[o] + v.y * w0[16 + o] + v.z * w0[32 + o] + v.w * w0[48 + o];
    }
    float* op = a1c + (size_t)idx * 16;
#pragma unroll
    for (int o = 0; o < 16; o += 4)
        *(float4*)(op + o) = make_float4(acc[o], acc[o+1], acc[o+2], acc[o+3]);
}

// ---------------- batched: a2 (recomputed) + agg=[mean,max] ----------------
__global__ void aggb_k(const float* __restrict__ feats, const float* __restrict__ w,
                       const float* __restrict__ b, const float* __restrict__ a1c,
                       float* __restrict__ agg, int4 xoff, int N) {
    __shared__ float wl[CC * 16];
    for (int i = threadIdx.x; i < CC * 16; i += 256) {
        int o = i % 16, c = i / 16;
        wl[i] = w[o * CC + c];
    }
    __syncthreads();
    int idx = blockIdx.x * 256 + threadIdx.x;
    if (idx >= N) return;
    int bi = idx / (NJ * HWD);
    int rem = idx - bi * (NJ * HWD);
    int n = rem / HWD, p = rem % HWD;
    int xo = sel4(xoff, bi);
    const float* f = feats + ((size_t)(n + xo) * HWD + p) * CC;
    float acc[16];
#pragma unroll
    for (int o = 0; o < 16; ++o) acc[o] = b[o];
#pragma unroll
    for (int cg = 0; cg < 8; ++cg) {
        float4 v = *(const float4*)(f + cg * 4);
        const float* w0 = &wl[cg * 4 * 16];
#pragma unroll
        for (int o = 0; o < 16; ++o)
            acc[o] += v.x * w0[o] + v.y * w0[16 + o] + v.z * w0[32 + o] + v.w * w0[48 + o];
    }
    float sum = 0.f, mx = -1e30f;
    const float* ap = a1c + (size_t)rem * 16;
#pragma unroll
    for (int o = 0; o < 16; ++o) {
        float v = ap[o];
        sum += v; mx = fmaxf(mx, v);
    }
#pragma unroll
    for (int o = 0; o < 16; ++o) {
        sum += acc[o]; mx = fmaxf(mx, acc[o]);
    }
    agg[(size_t)idx * 2 + 0] = sum * (1.f / 32.f);
    agg[(size_t)idx * 2 + 1] = mx;
}

// ---------------- batched: sig from agg 3x3; fused = [a1c*g0, a2*g1] ----------------
__global__ void sigfusedb_k(const float* __restrict__ agg, const float* __restrict__ sqw,
                            const float* __restrict__ sqb, const float* __restrict__ a1c,
                            const float* __restrict__ feats, const float* __restrict__ w,
                            const float* __restrict__ b, float* __restrict__ fused,
                            int4 xoff, int N) {
    __shared__ float wl[CC * 16];
    for (int i = threadIdx.x; i < CC * 16; i += 256) {
        int o = i % 16, c = i / 16;
        wl[i] = w[o * CC + c];
    }
    __syncthreads();
    int idx = blockIdx.x * 256 + threadIdx.x;
    if (idx >= N) return;
    int bi = idx / (NJ * HWD);
    int rem = idx - bi * (NJ * HWD);
    int n = rem / HWD, p = rem % HWD;
    int h = p / WD, q = p % WD;
    float s0 = sqb[0], s1 = sqb[1];
    const float* ag = agg + (size_t)(idx - p) * 2;
#pragma unroll
    for (int k = 0; k < 9; ++k) {
        int hh = h + k / 3 - 1, qq = q + k % 3 - 1;
        if (hh < 0 || hh >= WD || qq < 0 || qq >= WD) continue;
        float2 v = *(const float2*)(ag + (hh * WD + qq) * 2);
        s0 += v.x * sqw[0 * 18 + 0 * 9 + k] + v.y * sqw[0 * 18 + 1 * 9 + k];
        s1 += v.x * sqw[1 * 18 + 0 * 9 + k] + v.y * sqw[1 * 18 + 1 * 9 + k];
    }
    float g0 = sigm(s0), g1 = sigm(s1);
    int xo = sel4(xoff, bi);
    const float* f = feats + ((size_t)(n + xo) * HWD + p) * CC;
    float acc[16];
#pragma unroll
    for (int o = 0; o < 16; ++o) acc[o] = b[o];
#pragma unroll
    for (int cg = 0; cg < 8; ++cg) {
        float4 v = *(const float4*)(f + cg * 4);
        const float* w0 = &wl[cg * 4 * 16];
#pragma unroll
        for (int o = 0; o < 16; ++o)
            acc[o] += v.x * w0[o] + v.y * w0[16 + o] + v.z * w0[32 + o] + v.w * w0[48 + o];
    }
    const float* ap = a1c + (size_t)rem * 16;
    float* fp = fused + (size_t)idx * CC;
#pragma unroll
    for (int o = 0; o < 16; ++o) fp[o] = ap[o] * g0;
#pragma unroll
    for (int o = 0; o < 16; ++o) fp[16 + o] = acc[o] * g1;
}

// ---------------- batched deformable conv 3x3, 32->32, NHWC, 4 px/thread ----------------
__global__ __launch_bounds__(256, 2)
void deformb_k(const float* __restrict__ base_, const float* __restrict__ off,
               const float* __restrict__ w, float* __restrict__ out,
               int4 froff, int Npix) {
    __shared__ float wl[9 * CC * CC];
    for (int i = threadIdx.x; i < 9 * CC * CC; i += 256) {
        int o = i & 31, c = (i >> 5) & 31, kk = i >> 10;
        wl[i] = w[(o * CC + c) * 9 + kk];
    }
    __syncthreads();
    int pbase = (blockIdx.x * 256 + threadIdx.x) * 4;
    if (pbase >= Npix) return;
    const float* xf[4];
    const float* ofp[4];
    int h4[4], q4[4];
#pragma unroll
    for (int px = 0; px < 4; ++px) {
        int gid = pbase + px;
        int bi = gid / (NJ * HWD);
        int rem = gid - bi * (NJ * HWD);
        int n = rem / HWD, p = rem - n * HWD;
        h4[px] = p / WD; q4[px] = p - h4[px] * WD;
        xf[px] = base_ + (size_t)(n + sel4(froff, bi)) * HWD * CC;
        ofp[px] = off + (size_t)gid * 18;
    }
    float acc[4][CC];
#pragma unroll
    for (int px = 0; px < 4; ++px)
#pragma unroll
        for (int o = 0; o < CC; ++o) acc[px][o] = 0.f;

    for (int kk = 0; kk < 9; ++kk) {
        int ky = kk / 3, kx = kk - ky * 3;
        float w00[4], w01[4], w10[4], w11[4];
        int o00[4], o01[4], o10[4], o11[4];
#pragma unroll
        for (int px = 0; px < 4; ++px) {
            float2 d = *(const float2*)(ofp[px] + 2 * kk);
            float py = (float)(h4[px] - 1 + ky) + d.x;
            float pxx = (float)(q4[px] - 1 + kx) + d.y;
            float y0f = floorf(py), x0f = floorf(pxx);
            float ly = py - y0f, lx = pxx - x0f;
            int y0 = (int)y0f, x0 = (int)x0f;
            float a = (1.f - ly) * (1.f - lx), b = (1.f - ly) * lx;
            float c = ly * (1.f - lx), dd = ly * lx;
            bool yv0 = (y0 >= 0 && y0 < WD), yv1 = (y0 + 1 >= 0 && y0 + 1 < WD);
            bool xv0 = (x0 >= 0 && x0 < WD), xv1 = (x0 + 1 >= 0 && x0 + 1 < WD);
            w00[px] = (yv0 && xv0) ? a : 0.f;
            w01[px] = (yv0 && xv1) ? b : 0.f;
            w10[px] = (yv1 && xv0) ? c : 0.f;
            w11[px] = (yv1 && xv1) ? dd : 0.f;
            int yc0 = min(max(y0, 0), WD - 1), yc1 = min(max(y0 + 1, 0), WD - 1);
            int xc0 = min(max(x0, 0), WD - 1), xc1 = min(max(x0 + 1, 0), WD - 1);
            o00[px] = (yc0 * WD + xc0) * CC; o01[px] = (yc0 * WD + xc1) * CC;
            o10[px] = (yc1 * WD + xc0) * CC; o11[px] = (yc1 * WD + xc1) * CC;
        }
        const float* wk = &wl[kk * CC * CC];
#pragma unroll
        for (int cg = 0; cg < 8; ++cg) {
            float s[4][4];
#pragma unroll
            for (int px = 0; px < 4; ++px) {
                float4 a = *(const float4*)(xf[px] + o00[px] + cg * 4);
                float4 bb = *(const float4*)(xf[px] + o01[px] + cg * 4);
                float4 cc = *(const float4*)(xf[px] + o10[px] + cg * 4);
                float4 dd = *(const float4*)(xf[px] + o11[px] + cg * 4);
                s[px][0] = a.x * w00[px] + bb.x * w01[px] + cc.x * w10[px] + dd.x * w11[px];
                s[px][1] = a.y * w00[px] + bb.y * w01[px] + cc.y * w10[px] + dd.y * w11[px];
                s[px][2] = a.z * w00[px] + bb.z * w01[px] + cc.z * w10[px] + dd.z * w11[px];
                s[px][3] = a.w * w00[px] + bb.w * w01[px] + cc.w * w10[px] + dd.w * w11[px];
            }
            const float* w0 = wk + (cg * 4) * CC;
#pragma unroll
            for (int r = 0; r < 4; ++r) {
                const float* wr = w0 + r * CC;
#pragma unroll
                for (int px = 0; px < 4; ++px)
#pragma unroll
                    for (int o = 0; o < CC; ++o)
                        acc[px][o] += s[px][r] * wr[o];
            }
        }
    }
#pragma unroll
    for (int px = 0; px < 4; ++px) {
        float* op = out + (size_t)(pbase + px) * CC;
#pragma unroll
        for (int o = 0; o < CC; o += 4)
            *(float4*)(op + o) = make_float4(acc[px][o], acc[px][o+1], acc[px][o+2], acc[px][o+3]);
    }
}

// ---------------- batched 3x3 conv 32->1 into aligned channels ----------------
__global__ void convoutb_k(const float* __restrict__ in, const float* __restrict__ w,
                           const float* __restrict__ b, float* __restrict__ outA,
                           int4 cidx, int N) {
    __shared__ float wl[9 * CC];
    for (int i = threadIdx.x; i < 9 * CC; i += 256) {
        int k = i / CC, c = i % CC;
        wl[i] = w[c * 9 + k];
    }
    __syncthreads();
    int idx = blockIdx.x * 256 + threadIdx.x;
    if (idx >= N) return;
    int bi = idx / (NJ * HWD);
    int rem = idx - bi * (NJ * HWD);
    int n = rem / HWD, p = rem % HWD;
    int h = p / WD, q = p % WD;
    int fr = idx / HWD;
    const float* inn = in + (size_t)fr * HWD * CC;
    float acc = b[0];
#pragma unroll
    for (int k = 0; k < 9; ++k) {
        int hh = h + k / 3 - 1, qq = q + k % 3 - 1;
        if (hh < 0 || hh >= WD || qq < 0 || qq >= WD) continue;
        const float* ip = inn + (hh * WD + qq) * CC;
        const float* wk = &wl[k * CC];
#pragma unroll
        for (int cg = 0; cg < 8; ++cg) {
            float4 v = *(const float4*)(ip + cg * 4);
            acc += v.x * wk[cg*4] + v.y * wk[cg*4+1] + v.z * wk[cg*4+2] + v.w * wk[cg*4+3];
        }
    }
    outA[((size_t)n * 5 + sel4(cidx, bi)) * HWD + p] = acc;
}

// ---------------- cen_raw into aligned ch2 + arange output ----------------
__global__ void misc_k(const float* __restrict__ imgs, float* __restrict__ out) {
    int idx = blockIdx.x * 256 + threadIdx.x;
    float* alig = out + 135036 + 124;
    if (idx < NJ * HWD) {
        int n = idx / HWD, p = idx % HWD;
        alig[((size_t)n * 5 + 2) * HWD + p] = imgs[(size_t)(n + 2) * HWD + p];
    }
    if (idx < NJ) out[135036 + idx] = (float)(idx + 2);
}

extern "C" void kernel_launch(void* const* d_in, const int* in_sizes, int n_in,
                              void* d_out, int out_size, void* d_ws, size_t ws_size,
                              hipStream_t stream) {
    const float* x      = (const float*)d_in[0];
    const float* mlp_w  = (const float*)d_in[1];
    const float* mlp_b  = (const float*)d_in[2];
    const float* fe_w   = (const float*)d_in[3];
    const float* fe_b   = (const float*)d_in[4];
    const float* c0_w   = (const float*)d_in[5];
    const float* c0_b   = (const float*)d_in[6];
    const float* c1_w   = (const float*)d_in[7];
    const float* c1_b   = (const float*)d_in[8];
    const float* sq_w   = (const float*)d_in[9];
    const float* sq_b   = (const float*)d_in[10];
    const float* off1_w = (const float*)d_in[11];
    const float* off1_b = (const float*)d_in[12];
    const float* dw1    = (const float*)d_in[13];
    const float* off2_w = (const float*)d_in[14];
    const float* off2_b = (const float*)d_in[15];
    const float* dw2    = (const float*)d_in[16];
    const float* conv_w = (const float*)d_in[17];
    const float* conv_b = (const float*)d_in[18];
    const float* tc0_w  = (const float*)d_in[19];
    const float* tc0_b  = (const float*)d_in[20];
    const float* rb_w1  = (const float*)d_in[21];
    const float* rb_b1  = (const float*)d_in[22];
    const float* rb_w2  = (const float*)d_in[23];
    const float* rb_b2  = (const float*)d_in[24];
    const float* tail_w = (const float*)d_in[25];

    const size_t FRAME = (size_t)NJ * HWD;  // 135036
    const size_t baseN = 1089 + (size_t)NF * HWD + (size_t)NF * HWD * CC + FRAME * 16;
    const size_t perB  = FRAME * 2 + FRAME * 32 + FRAME * 18 + FRAME * 32;
    int nb = 4;
    while (nb > 1 && (baseN + (size_t)nb * perB) * 4 > ws_size) nb >>= 1;

    float* ws = (float*)d_ws;
    float* rs    = ws;
    float* imgs  = rs + 1089;
    float* feats = imgs + NF * HWD;
    float* a1c   = feats + (size_t)NF * HWD * CC;
    float* agg   = a1c + FRAME * 16;
    float* fused = agg + (size_t)nb * FRAME * 2;
    float* offb  = fused + (size_t)nb * FRAME * 32;
    float* al1   = offb + (size_t)nb * FRAME * 18;
    float* al2   = fused;
    float* hbuf  = feats;
    float* tmp   = fused;

    float* outF = (float*)d_out;
    float* outA = outF + 135036 + 124;

    const int GF = (NF * HWD + 255) / 256;
    const int GJ = (NJ * HWD + 255) / 256;

    rowsum_k<<<HWD, 256, 0, stream>>>(mlp_w, rs);
    imgs_k<<<GF, 256, 0, stream>>>(x, rs, mlp_b, imgs);
    conv3x3_chwin<1, 32, true><<<GF, 256, 0, stream>>>(imgs, HWD, fe_w, fe_b, feats, NF);
    a1c_k<<<GJ, 256, 0, stream>>>(feats, c0_w, c0_b, a1c);

    const int xoffs_all[4] = {0, 1, 3, 4};
    const int cidx_all[4]  = {0, 1, 3, 4};
    for (int pb = 0; pb < 4; pb += nb) {
        int4 xo = make_int4(xoffs_all[pb],
                            xoffs_all[(pb + 1) & 3],
                            xoffs_all[(pb + 2) & 3],
                            xoffs_all[(pb + 3) & 3]);
        int4 ci = make_int4(cidx_all[pb],
                            cidx_all[(pb + 1) & 3],
                            cidx_all[(pb + 2) & 3],
                            cidx_all[(pb + 3) & 3]);
        int4 f2 = make_int4(0, NJ, 2 * NJ, 3 * NJ);
        int N = nb * (int)FRAME;
        int GB  = (N + 255) / 256;
        int GB4 = (N / 4 + 255) / 256;
        aggb_k<<<GB, 256, 0, stream>>>(feats, c1_w, c1_b, a1c, agg, xo, N);
        sigfusedb_k<<<GB, 256, 0, stream>>>(agg, sq_w, sq_b, a1c, feats, c1_w, c1_b, fused, xo, N);
        conv3x3_nhwc<32, 18, 4, false, true, false><<<GB4, 256, 0, stream>>>(
            fused, off1_w, off1_b, nullptr, 0, 0, offb, 18, HWD * 18, N);
        deformb_k<<<GB4, 256, 0, stream>>>(feats, offb, dw1, al1, xo, N);
        conv3x3_nhwc<32, 18, 4, false, true, false><<<GB4, 256, 0, stream>>>(
            al1, off2_w, off2_b, nullptr, 0, 0, offb, 18, HWD * 18, N);
        deformb_k<<<GB4, 256, 0, stream>>>(al1, offb, dw2, al2, f2, N);
        convoutb_k<<<GB, 256, 0, stream>>>(al2, conv_w, conv_b, outA, ci, N);
    }

    misc_k<<<GJ, 256, 0, stream>>>(imgs, outF);

    const int G2 = ((int)FRAME / 2 + 255) / 256;
    conv3x3_chwin<5, 32, true><<<GJ, 256, 0, stream>>>(outA, 5 * HWD, tc0_w, tc0_b, hbuf, NJ);
    for (int l = 0; l < 5; ++l) {
        conv3x3_nhwc<32, 32, 2, true, true, false><<<G2, 256, 0, stream>>>(
            hbuf, rb_w1 + (size_t)l * CC * CC * 9, rb_b1 + l * CC,
            nullptr, 0, 0, tmp, CC, HWD * CC, (int)FRAME);
        conv3x3_nhwc<32, 32, 2, false, true, true><<<G2, 256, 0, stream>>>(
            tmp, rb_w2 + (size_t)l * CC * CC * 9, rb_b2 + l * CC,
            hbuf, CC, HWD * CC, hbuf, CC, HWD * CC, (int)FRAME);
    }
    conv3x3_nhwc<32, 1, 2, false, false, false><<<G2, 256, 0, stream>>>(
        hbuf, tail_w, nullptr, nullptr, 0, 0, outF, 1, HWD, (int)FRAME);
}

// Round 6
// 1399.122 us; speedup vs baseline: 19.6625x; 19.6625x over previous
//
#include <hip/hip_runtime.h>
#include <math.h>

#define HWD 1089
#define WD 33
#define NF 128
#define NJ 124
#define CC 32

typedef __attribute__((ext_vector_type(8))) short s16x8;
typedef __attribute__((ext_vector_type(4))) float f32x4;

__device__ __forceinline__ float sigm(float z) { return 1.f / (1.f + expf(-z)); }
__device__ __forceinline__ int sel4(int4 v, int i) { return i == 0 ? v.x : i == 1 ? v.y : i == 2 ? v.z : v.w; }
__device__ __forceinline__ short f2b(float f) {
    union { float f; unsigned u; } x; x.f = f;
    unsigned r = x.u + 0x7fffu + ((x.u >> 16) & 1u);
    return (short)(r >> 16);
}

// ---------------- rs[j] = sum_k mlp_w[j][k] ----------------
__global__ void rowsum_k(const float* __restrict__ mw, float* __restrict__ rs) {
    int j = blockIdx.x;
    const float* row = mw + (size_t)j * HWD;
    float s = 0.f;
    for (int k = threadIdx.x; k < HWD; k += 256) s += row[k];
    __shared__ float red[256];
    red[threadIdx.x] = s; __syncthreads();
    for (int off = 128; off > 0; off >>= 1) {
        if (threadIdx.x < off) red[threadIdx.x] += red[threadIdx.x + off];
        __syncthreads();
    }
    if (threadIdx.x == 0) rs[j] = red[0];
}

// ---------------- imgs = x * sigmoid((t/20)*rs + mlp_b) ----------------
__global__ void imgs_k(const float* __restrict__ x, const float* __restrict__ rs,
                       const float* __restrict__ mb, float* __restrict__ imgs) {
    int idx = blockIdx.x * 256 + threadIdx.x;
    if (idx >= NF * HWD) return;
    int t = idx / HWD, p = idx % HWD;
    float pe = sigm(((float)t / 20.0f) * rs[p] + mb[p]);
    imgs[idx] = x[idx] * pe;
}

// ---------------- weight pack: 12 tensors -> bf16 MFMA B-fragments ----------------
// tensor t: 0=off1_w(18) 1=off2_w(18) 2..6=rb_w1[l](32) 7..11=rb_w2[l](32)
__global__ void pack_k(const float* __restrict__ off1_w, const float* __restrict__ off2_w,
                       const float* __restrict__ rb_w1, const float* __restrict__ rb_w2,
                       unsigned short* __restrict__ wp) {
    int tid = blockIdx.x * 256 + threadIdx.x;
    if (tid >= 12 * 9216) return;
    int t = tid / 9216, u = tid - t * 9216;
    int j = u & 7, l = (u >> 3) & 63, h = (u >> 9) & 1, k = u >> 10;
    int o = h * 16 + (l & 15);
    int c = 8 * (l >> 4) + j;
    const float* src;
    int cout;
    if (t == 0)      { src = off1_w; cout = 18; }
    else if (t == 1) { src = off2_w; cout = 18; }
    else if (t < 7)  { src = rb_w1 + (size_t)(t - 2) * 9216; cout = 32; }
    else             { src = rb_w2 + (size_t)(t - 7) * 9216; cout = 32; }
    float val = (o < cout) ? src[(o * 32 + c) * 9 + k] : 0.f;
    wp[tid] = (unsigned short)f2b(val);
}

// ---------------- MFMA 3x3 conv, 32-in NHWC fp32, COUT out ----------------
template <int COUT, bool RELU, bool HAS_RES>
__global__ __launch_bounds__(256, 1)
void mfmaconv_k(const float* __restrict__ in, const unsigned short* __restrict__ wp,
                const float* __restrict__ bias, const float* __restrict__ res,
                float* __restrict__ out, int out_ps, int Npix) {
    int lane = threadIdx.x & 63;
    int wav  = threadIdx.x >> 6;
    int pix0 = (blockIdx.x * 4 + wav) * 16;
    if (pix0 >= Npix) return;
    // B fragments: 9 taps x 2 o-halves, resident in VGPRs
    s16x8 bf[18];
#pragma unroll
    for (int i = 0; i < 18; ++i)
        bf[i] = *(const s16x8*)(wp + ((size_t)(i * 64 + lane)) * 8);
    // A-side geometry: this lane supplies row m=lane&15, channels 8*(lane>>4)..+8
    int am = lane & 15;
    int ak = lane >> 4;
    int apix = pix0 + am;
    bool aval = apix < Npix;
    int ap = apix % HWD;
    int ah = ap / WD, aq = ap - ah * WD;
    const float* abase = in + (size_t)apix * 32 + ak * 8;
    f32x4 acc0 = {0.f, 0.f, 0.f, 0.f};
    f32x4 acc1 = {0.f, 0.f, 0.f, 0.f};
#pragma unroll
    for (int k = 0; k < 9; ++k) {
        int dy = k / 3 - 1, dx = k % 3 - 1;
        int hh = ah + dy, qq = aq + dx;
        bool v = aval && hh >= 0 && hh < WD && qq >= 0 && qq < WD;
        s16x8 af = {0, 0, 0, 0, 0, 0, 0, 0};
        if (v) {
            const float* ipp = abase + (dy * WD + dx) * 32;
            float4 u0 = *(const float4*)(ipp);
            float4 u1 = *(const float4*)(ipp + 4);
            af[0] = f2b(u0.x); af[1] = f2b(u0.y); af[2] = f2b(u0.z); af[3] = f2b(u0.w);
            af[4] = f2b(u1.x); af[5] = f2b(u1.y); af[6] = f2b(u1.z); af[7] = f2b(u1.w);
        }
        acc0 = __builtin_amdgcn_mfma_f32_16x16x32_bf16(af, bf[k * 2 + 0], acc0, 0, 0, 0);
        acc1 = __builtin_amdgcn_mfma_f32_16x16x32_bf16(af, bf[k * 2 + 1], acc1, 0, 0, 0);
    }
    // store: D[m][n], n = lane&15, m = 4*(lane>>4)+i
    int n = lane & 15;
    int mrow = (lane >> 4) * 4;
    float b0 = bias[n];
    float b1 = (16 + n < COUT) ? bias[16 + n] : 0.f;
#pragma unroll
    for (int i = 0; i < 4; ++i) {
        int pix = pix0 + mrow + i;
        if (pix >= Npix) continue;
        float v0 = acc0[i] + b0;
        if (RELU) v0 = fmaxf(v0, 0.f);
        if (HAS_RES) v0 += res[(size_t)pix * 32 + n];
        out[(size_t)pix * out_ps + n] = v0;
        if (16 + n < COUT) {
            float v1 = acc1[i] + b1;
            if (RELU) v1 = fmaxf(v1, 0.f);
            if (HAS_RES) v1 += res[(size_t)pix * 32 + 16 + n];
            out[(size_t)pix * out_ps + 16 + n] = v1;
        }
    }
}

// ---------------- 3x3 conv NHWC (R4 form, 1 px/thread) — tail use ----------------
template <int CIN, int COUT, bool RELU, bool HAS_B, bool HAS_RES>
__global__ __launch_bounds__(256, 2)
void conv3x3_nhwc(const float* __restrict__ in,
                  const float* __restrict__ w, const float* __restrict__ b,
                  const float* __restrict__ res, int res_ps, int res_ns,
                  float* __restrict__ out, int out_ps, int out_ns, int N) {
    constexpr int WROW = (COUT + 3) & ~3;
    __shared__ float wl[9 * CIN * WROW];
    for (int i = threadIdx.x; i < 9 * CIN * WROW; i += 256) {
        int o = i % WROW, r = i / WROW;
        int c = r % CIN, k = r / CIN;
        wl[i] = (o < COUT) ? w[(o * CIN + c) * 9 + k] : 0.f;
    }
    __syncthreads();
    int idx = blockIdx.x * 256 + threadIdx.x;
    if (idx >= N * HWD) return;
    int n = idx / HWD, p = idx % HWD;
    int h = p / WD, q = p % WD;
    float acc[COUT];
#pragma unroll
    for (int o = 0; o < COUT; ++o) acc[o] = HAS_B ? b[o] : 0.f;
    const float* inn = in + (size_t)n * HWD * CIN;
#pragma unroll
    for (int k = 0; k < 9; ++k) {
        int hh = h + k / 3 - 1, qq = q + k % 3 - 1;
        if (hh < 0 || hh >= WD || qq < 0 || qq >= WD) continue;
        const float* ip = inn + (hh * WD + qq) * CIN;
        const float* wk = &wl[k * CIN * WROW];
#pragma unroll
        for (int cg = 0; cg < CIN / 4; ++cg) {
            float4 v = *(const float4*)(ip + cg * 4);
            const float* w0 = wk + (cg * 4) * WROW;
#pragma unroll
            for (int o = 0; o < COUT; ++o)
                acc[o] += v.x * w0[o] + v.y * w0[WROW + o]
                        + v.z * w0[2 * WROW + o] + v.w * w0[3 * WROW + o];
        }
    }
#pragma unroll
    for (int o = 0; o < COUT; ++o) {
        float val = acc[o];
        if (RELU) val = fmaxf(val, 0.f);
        if (HAS_RES) val += res[(size_t)n * res_ns + (size_t)p * res_ps + o];
        out[(size_t)n * out_ns + (size_t)p * out_ps + o] = val;
    }
}

// ---------------- 3x3 conv, CHW input (fe 1->32, tc0 5->32), NHWC out ----------------
template <int CIN, int COUT, bool RELU>
__global__ __launch_bounds__(256, 2)
void conv3x3_chwin(const float* __restrict__ in, int in_ns,
                   const float* __restrict__ w, const float* __restrict__ b,
                   float* __restrict__ out, int N) {
    __shared__ float wl[CIN * 9 * COUT];
    for (int i = threadIdx.x; i < CIN * 9 * COUT; i += 256) {
        int o = i % COUT, r = i / COUT;
        int k = r % 9, c = r / 9;
        wl[i] = w[(o * CIN + c) * 9 + k];
    }
    __syncthreads();
    int idx = blockIdx.x * 256 + threadIdx.x;
    if (idx >= N * HWD) return;
    int n = idx / HWD, p = idx % HWD;
    int h = p / WD, q = p % WD;
    float acc[COUT];
#pragma unroll
    for (int o = 0; o < COUT; ++o) acc[o] = b[o];
    const float* inn = in + (size_t)n * in_ns;
#pragma unroll
    for (int c = 0; c < CIN; ++c) {
#pragma unroll
        for (int k = 0; k < 9; ++k) {
            int hh = h + k / 3 - 1, qq = q + k % 3 - 1;
            if (hh < 0 || hh >= WD || qq < 0 || qq >= WD) continue;
            float v = inn[c * HWD + hh * WD + qq];
            const float* wp = &wl[(c * 9 + k) * COUT];
#pragma unroll
            for (int o = 0; o < COUT; ++o) acc[o] += v * wp[o];
        }
    }
    float* op = out + ((size_t)idx) * COUT;
#pragma unroll
    for (int o = 0; o < COUT; ++o) op[o] = RELU ? fmaxf(acc[o], 0.f) : acc[o];
}

// ---------------- a1c = 1x1 conv (16 out) of feats[n+2], NHWC ----------------
__global__ void a1c_k(const float* __restrict__ feats, const float* __restrict__ w,
                      const float* __restrict__ b, float* __restrict__ a1c) {
    __shared__ float wl[CC * 16];
    for (int i = threadIdx.x; i < CC * 16; i += 256) {
        int o = i % 16, c = i / 16;
        wl[i] = w[o * CC + c];
    }
    __syncthreads();
    int idx = blockIdx.x * 256 + threadIdx.x;
    if (idx >= NJ * HWD) return;
    int n = idx / HWD, p = idx % HWD;
    const float* f = feats + ((size_t)(n + 2) * HWD + p) * CC;
    float acc[16];
#pragma unroll
    for (int o = 0; o < 16; ++o) acc[o] = b[o];
#pragma unroll
    for (int cg = 0; cg < 8; ++cg) {
        float4 v = *(const float4*)(f + cg * 4);
        const float* w0 = &wl[cg * 4 * 16];
#pragma unroll
        for (int o = 0; o < 16; ++o)
            acc[o] += v.x * w0[o] + v.y * w0[16 + o] + v.z * w0[32 + o] + v.w * w0[48 + o];
    }
    float* op = a1c + (size_t)idx * 16;
#pragma unroll
    for (int o = 0; o < 16; o += 4)
        *(float4*)(op + o) = make_float4(acc[o], acc[o+1], acc[o+2], acc[o+3]);
}

// ---------------- batched: a2 (recomputed) + agg=[mean,max] ----------------
__global__ void aggb_k(const float* __restrict__ feats, const float* __restrict__ w,
                       const float* __restrict__ b, const float* __restrict__ a1c,
                       float* __restrict__ agg, int4 xoff, int N) {
    __shared__ float wl[CC * 16];
    for (int i = threadIdx.x; i < CC * 16; i += 256) {
        int o = i % 16, c = i / 16;
        wl[i] = w[o * CC + c];
    }
    __syncthreads();
    int idx = blockIdx.x * 256 + threadIdx.x;
    if (idx >= N) return;
    int bi = idx / (NJ * HWD);
    int rem = idx - bi * (NJ * HWD);
    int n = rem / HWD, p = rem % HWD;
    int xo = sel4(xoff, bi);
    const float* f = feats + ((size_t)(n + xo) * HWD + p) * CC;
    float acc[16];
#pragma unroll
    for (int o = 0; o < 16; ++o) acc[o] = b[o];
#pragma unroll
    for (int cg = 0; cg < 8; ++cg) {
        float4 v = *(const float4*)(f + cg * 4);
        const float* w0 = &wl[cg * 4 * 16];
#pragma unroll
        for (int o = 0; o < 16; ++o)
            acc[o] += v.x * w0[o] + v.y * w0[16 + o] + v.z * w0[32 + o] + v.w * w0[48 + o];
    }
    float sum = 0.f, mx = -1e30f;
    const float* ap = a1c + (size_t)rem * 16;
#pragma unroll
    for (int o = 0; o < 16; ++o) {
        float v = ap[o];
        sum += v; mx = fmaxf(mx, v);
    }
#pragma unroll
    for (int o = 0; o < 16; ++o) {
        sum += acc[o]; mx = fmaxf(mx, acc[o]);
    }
    agg[(size_t)idx * 2 + 0] = sum * (1.f / 32.f);
    agg[(size_t)idx * 2 + 1] = mx;
}

// ---------------- batched: sig from agg 3x3; fused = [a1c*g0, a2*g1] ----------------
__global__ void sigfusedb_k(const float* __restrict__ agg, const float* __restrict__ sqw,
                            const float* __restrict__ sqb, const float* __restrict__ a1c,
                            const float* __restrict__ feats, const float* __restrict__ w,
                            const float* __restrict__ b, float* __restrict__ fused,
                            int4 xoff, int N) {
    __shared__ float wl[CC * 16];
    for (int i = threadIdx.x; i < CC * 16; i += 256) {
        int o = i % 16, c = i / 16;
        wl[i] = w[o * CC + c];
    }
    __syncthreads();
    int idx = blockIdx.x * 256 + threadIdx.x;
    if (idx >= N) return;
    int bi = idx / (NJ * HWD);
    int rem = idx - bi * (NJ * HWD);
    int n = rem / HWD, p = rem % HWD;
    int h = p / WD, q = p % WD;
    float s0 = sqb[0], s1 = sqb[1];
    const float* ag = agg + (size_t)(idx - p) * 2;
#pragma unroll
    for (int k = 0; k < 9; ++k) {
        int hh = h + k / 3 - 1, qq = q + k % 3 - 1;
        if (hh < 0 || hh >= WD || qq < 0 || qq >= WD) continue;
        float2 v = *(const float2*)(ag + (hh * WD + qq) * 2);
        s0 += v.x * sqw[0 * 18 + 0 * 9 + k] + v.y * sqw[0 * 18 + 1 * 9 + k];
        s1 += v.x * sqw[1 * 18 + 0 * 9 + k] + v.y * sqw[1 * 18 + 1 * 9 + k];
    }
    float g0 = sigm(s0), g1 = sigm(s1);
    int xo = sel4(xoff, bi);
    const float* f = feats + ((size_t)(n + xo) * HWD + p) * CC;
    float acc[16];
#pragma unroll
    for (int o = 0; o < 16; ++o) acc[o] = b[o];
#pragma unroll
    for (int cg = 0; cg < 8; ++cg) {
        float4 v = *(const float4*)(f + cg * 4);
        const float* w0 = &wl[cg * 4 * 16];
#pragma unroll
        for (int o = 0; o < 16; ++o)
            acc[o] += v.x * w0[o] + v.y * w0[16 + o] + v.z * w0[32 + o] + v.w * w0[48 + o];
    }
    const float* ap = a1c + (size_t)rem * 16;
    float* fp = fused + (size_t)idx * CC;
#pragma unroll
    for (int o = 0; o < 16; ++o) fp[o] = ap[o] * g0;
#pragma unroll
    for (int o = 0; o < 16; ++o) fp[16 + o] = acc[o] * g1;
}

// ---------------- batched deformable conv 3x3, 32->32, NHWC (R4, 1 px/thread) ----------------
__global__ __launch_bounds__(256, 2)
void deformb_k(const float* __restrict__ base_, const float* __restrict__ off,
               const float* __restrict__ w, float* __restrict__ out,
               int4 froff, int N) {
    __shared__ float wl[9 * CC * CC];
    for (int i = threadIdx.x; i < 9 * CC * CC; i += 256) {
        int o = i & 31, c = (i >> 5) & 31, kk = i >> 10;
        wl[i] = w[(o * CC + c) * 9 + kk];
    }
    __syncthreads();
    int idx = blockIdx.x * 256 + threadIdx.x;
    if (idx >= N) return;
    int bi = idx / (NJ * HWD);
    int rem = idx - bi * (NJ * HWD);
    int n = rem / HWD, p = rem % HWD;
    int h = p / WD, q = p % WD;
    const float* xf = base_ + (size_t)(n + sel4(froff, bi)) * HWD * CC;
    const float* ofp = off + (size_t)idx * 18;
    float ofv[18];
#pragma unroll
    for (int i = 0; i < 18; i += 2) {
        float2 t = *(const float2*)(ofp + i);
        ofv[i] = t.x; ofv[i + 1] = t.y;
    }
    float acc[CC];
#pragma unroll
    for (int o = 0; o < CC; ++o) acc[o] = 0.f;
#pragma unroll
    for (int kk = 0; kk < 9; ++kk) {
        float py = (float)(h - 1 + kk / 3) + ofv[2 * kk];
        float px = (float)(q - 1 + kk % 3) + ofv[2 * kk + 1];
        float y0f = floorf(py), x0f = floorf(px);
        float ly = py - y0f, lx = px - x0f;
        int y0 = (int)y0f, x0 = (int)x0f;
        float w00 = (1.f - ly) * (1.f - lx), w01 = (1.f - ly) * lx;
        float w10 = ly * (1.f - lx), w11 = ly * lx;
        bool yv0 = (y0 >= 0 && y0 < WD), yv1 = (y0 + 1 >= 0 && y0 + 1 < WD);
        bool xv0 = (x0 >= 0 && x0 < WD), xv1 = (x0 + 1 >= 0 && x0 + 1 < WD);
        if (!(yv0 && xv0)) w00 = 0.f;
        if (!(yv0 && xv1)) w01 = 0.f;
        if (!(yv1 && xv0)) w10 = 0.f;
        if (!(yv1 && xv1)) w11 = 0.f;
        int yc0 = min(max(y0, 0), WD - 1), yc1 = min(max(y0 + 1, 0), WD - 1);
        int xc0 = min(max(x0, 0), WD - 1), xc1 = min(max(x0 + 1, 0), WD - 1);
        const float* p00 = xf + (yc0 * WD + xc0) * CC;
        const float* p01 = xf + (yc0 * WD + xc1) * CC;
        const float* p10 = xf + (yc1 * WD + xc0) * CC;
        const float* p11 = xf + (yc1 * WD + xc1) * CC;
        const float* wk = &wl[kk * CC * CC];
#pragma unroll
        for (int cg = 0; cg < 8; ++cg) {
            float4 a = *(const float4*)(p00 + cg * 4);
            float4 bb = *(const float4*)(p01 + cg * 4);
            float4 cc = *(const float4*)(p10 + cg * 4);
            float4 dd = *(const float4*)(p11 + cg * 4);
            float s0 = a.x * w00 + bb.x * w01 + cc.x * w10 + dd.x * w11;
            float s1 = a.y * w00 + bb.y * w01 + cc.y * w10 + dd.y * w11;
            float s2 = a.z * w00 + bb.z * w01 + cc.z * w10 + dd.z * w11;
            float s3 = a.w * w00 + bb.w * w01 + cc.w * w10 + dd.w * w11;
            const float* w0 = wk + (cg * 4) * CC;
#pragma unroll
            for (int o = 0; o < CC; ++o)
                acc[o] += s0 * w0[o] + s1 * w0[CC + o] + s2 * w0[2 * CC + o] + s3 * w0[3 * CC + o];
        }
    }
    float* op = out + (size_t)idx * CC;
#pragma unroll
    for (int o = 0; o < CC; o += 4)
        *(float4*)(op + o) = make_float4(acc[o], acc[o+1], acc[o+2], acc[o+3]);
}

// ---------------- batched 3x3 conv 32->1 into aligned channels ----------------
__global__ void convoutb_k(const float* __restrict__ in, const float* __restrict__ w,
                           const float* __restrict__ b, float* __restrict__ outA,
                           int4 cidx, int N) {
    __shared__ float wl[9 * CC];
    for (int i = threadIdx.x; i < 9 * CC; i += 256) {
        int k = i / CC, c = i % CC;
        wl[i] = w[c * 9 + k];
    }
    __syncthreads();
    int idx = blockIdx.x * 256 + threadIdx.x;
    if (idx >= N) return;
    int bi = idx / (NJ * HWD);
    int rem = idx - bi * (NJ * HWD);
    int n = rem / HWD, p = rem % HWD;
    int h = p / WD, q = p % WD;
    int fr = idx / HWD;
    const float* inn = in + (size_t)fr * HWD * CC;
    float acc = b[0];
#pragma unroll
    for (int k = 0; k < 9; ++k) {
        int hh = h + k / 3 - 1, qq = q + k % 3 - 1;
        if (hh < 0 || hh >= WD || qq < 0 || qq >= WD) continue;
        const float* ip = inn + (hh * WD + qq) * CC;
        const float* wk = &wl[k * CC];
#pragma unroll
        for (int cg = 0; cg < 8; ++cg) {
            float4 v = *(const float4*)(ip + cg * 4);
            acc += v.x * wk[cg*4] + v.y * wk[cg*4+1] + v.z * wk[cg*4+2] + v.w * wk[cg*4+3];
        }
    }
    outA[((size_t)n * 5 + sel4(cidx, bi)) * HWD + p] = acc;
}

// ---------------- cen_raw into aligned ch2 + arange output ----------------
__global__ void misc_k(const float* __restrict__ imgs, float* __restrict__ out) {
    int idx = blockIdx.x * 256 + threadIdx.x;
    float* alig = out + 135036 + 124;
    if (idx < NJ * HWD) {
        int n = idx / HWD, p = idx % HWD;
        alig[((size_t)n * 5 + 2) * HWD + p] = imgs[(size_t)(n + 2) * HWD + p];
    }
    if (idx < NJ) out[135036 + idx] = (float)(idx + 2);
}

extern "C" void kernel_launch(void* const* d_in, const int* in_sizes, int n_in,
                              void* d_out, int out_size, void* d_ws, size_t ws_size,
                              hipStream_t stream) {
    const float* x      = (const float*)d_in[0];
    const float* mlp_w  = (const float*)d_in[1];
    const float* mlp_b  = (const float*)d_in[2];
    const float* fe_w   = (const float*)d_in[3];
    const float* fe_b   = (const float*)d_in[4];
    const float* c0_w   = (const float*)d_in[5];
    const float* c0_b   = (const float*)d_in[6];
    const float* c1_w   = (const float*)d_in[7];
    const float* c1_b   = (const float*)d_in[8];
    const float* sq_w   = (const float*)d_in[9];
    const float* sq_b   = (const float*)d_in[10];
    const float* off1_w = (const float*)d_in[11];
    const float* off1_b = (const float*)d_in[12];
    const float* dw1    = (const float*)d_in[13];
    const float* off2_w = (const float*)d_in[14];
    const float* off2_b = (const float*)d_in[15];
    const float* dw2    = (const float*)d_in[16];
    const float* conv_w = (const float*)d_in[17];
    const float* conv_b = (const float*)d_in[18];
    const float* tc0_w  = (const float*)d_in[19];
    const float* tc0_b  = (const float*)d_in[20];
    const float* rb_w1  = (const float*)d_in[21];
    const float* rb_b1  = (const float*)d_in[22];
    const float* rb_w2  = (const float*)d_in[23];
    const float* rb_b2  = (const float*)d_in[24];
    const float* tail_w = (const float*)d_in[25];

    const size_t FRAME = (size_t)NJ * HWD;  // 135036
    const size_t baseN = 1089 + (size_t)NF * HWD + (size_t)NF * HWD * CC + FRAME * 16;
    const size_t perB  = FRAME * 2 + FRAME * 32 + FRAME * 18 + FRAME * 32;
    int nb = 4;
    while (nb > 1 && (baseN + (size_t)nb * perB) * 4 > ws_size) nb >>= 1;

    float* ws = (float*)d_ws;
    float* rs    = ws;
    float* imgs  = rs + 1089;
    float* feats = imgs + NF * HWD;
    float* a1c   = feats + (size_t)NF * HWD * CC;
    float* agg   = a1c + FRAME * 16;
    float* fused = agg + (size_t)nb * FRAME * 2;
    float* offb  = fused + (size_t)nb * FRAME * 32;
    float* al1   = offb + (size_t)nb * FRAME * 18;
    float* al2   = fused;
    float* hbuf  = feats;
    float* tmp   = fused;
    // weight-pack region overlaps imgs (dead after misc_k); 16B-aligned
    unsigned short* wpack = (unsigned short*)(((uintptr_t)imgs + 63) & ~(uintptr_t)63);
    unsigned short* wp_off1 = wpack + 0 * 9216;
    unsigned short* wp_off2 = wpack + 1 * 9216;
    // rb1[l] at (2+l)*9216, rb2[l] at (7+l)*9216

    float* outF = (float*)d_out;
    float* outA = outF + 135036 + 124;

    const int GF = (NF * HWD + 255) / 256;
    const int GJ = (NJ * HWD + 255) / 256;

    rowsum_k<<<HWD, 256, 0, stream>>>(mlp_w, rs);
    imgs_k<<<GF, 256, 0, stream>>>(x, rs, mlp_b, imgs);
    conv3x3_chwin<1, 32, true><<<GF, 256, 0, stream>>>(imgs, HWD, fe_w, fe_b, feats, NF);
    misc_k<<<GJ, 256, 0, stream>>>(imgs, outF);           // last reader of imgs
    pack_k<<<(12 * 9216 + 255) / 256, 256, 0, stream>>>(off1_w, off2_w, rb_w1, rb_w2, wpack);
    a1c_k<<<GJ, 256, 0, stream>>>(feats, c0_w, c0_b, a1c);

    const int xoffs_all[4] = {0, 1, 3, 4};
    const int cidx_all[4]  = {0, 1, 3, 4};
    for (int pb = 0; pb < 4; pb += nb) {
        int4 xo = make_int4(xoffs_all[pb],
                            xoffs_all[(pb + 1) & 3],
                            xoffs_all[(pb + 2) & 3],
                            xoffs_all[(pb + 3) & 3]);
        int4 ci = make_int4(cidx_all[pb],
                            cidx_all[(pb + 1) & 3],
                            cidx_all[(pb + 2) & 3],
                            cidx_all[(pb + 3) & 3]);
        int4 f2 = make_int4(0, NJ, 2 * NJ, 3 * NJ);
        int N = nb * (int)FRAME;
        int GB  = (N + 255) / 256;
        int GM  = (N + 63) / 64;       // MFMA conv: 64 pixels per block
        aggb_k<<<GB, 256, 0, stream>>>(feats, c1_w, c1_b, a1c, agg, xo, N);
        sigfusedb_k<<<GB, 256, 0, stream>>>(agg, sq_w, sq_b, a1c, feats, c1_w, c1_b, fused, xo, N);
        mfmaconv_k<18, false, false><<<GM, 256, 0, stream>>>(
            fused, wp_off1, off1_b, nullptr, offb, 18, N);
        deformb_k<<<GB, 256, 0, stream>>>(feats, offb, dw1, al1, xo, N);
        mfmaconv_k<18, false, false><<<GM, 256, 0, stream>>>(
            al1, wp_off2, off2_b, nullptr, offb, 18, N);
        deformb_k<<<GB, 256, 0, stream>>>(al1, offb, dw2, al2, f2, N);
        convoutb_k<<<GB, 256, 0, stream>>>(al2, conv_w, conv_b, outA, ci, N);
    }

    conv3x3_chwin<5, 32, true><<<GJ, 256, 0, stream>>>(outA, 5 * HWD, tc0_w, tc0_b, hbuf, NJ);
    const int GMF = ((int)FRAME + 63) / 64;
    for (int l = 0; l < 5; ++l) {
        mfmaconv_k<32, true, false><<<GMF, 256, 0, stream>>>(
            hbuf, wpack + (size_t)(2 + l) * 9216, rb_b1 + l * CC, nullptr, tmp, 32, (int)FRAME);
        mfmaconv_k<32, false, true><<<GMF, 256, 0, stream>>>(
            tmp, wpack + (size_t)(7 + l) * 9216, rb_b2 + l * CC, hbuf, hbuf, 32, (int)FRAME);
    }
    conv3x3_nhwc<32, 1, false, false, false><<<GJ, 256, 0, stream>>>(
        hbuf, tail_w, nullptr, nullptr, 0, 0, outF, 1, HWD, NJ);
}

// Round 7
// 1268.012 us; speedup vs baseline: 21.6956x; 1.1034x over previous
//
#include <hip/hip_runtime.h>
#include <math.h>

#define HWD 1089
#define WD 33
#define NF 128
#define NJ 124
#define CC 32

typedef __attribute__((ext_vector_type(8))) short s16x8;
typedef __attribute__((ext_vector_type(4))) float f32x4;

__device__ __forceinline__ float sigm(float z) { return 1.f / (1.f + expf(-z)); }
__device__ __forceinline__ int sel4(int4 v, int i) { return i == 0 ? v.x : i == 1 ? v.y : i == 2 ? v.z : v.w; }
__device__ __forceinline__ short f2b(float f) {
    union { float f; unsigned u; } x; x.f = f;
    unsigned r = x.u + 0x7fffu + ((x.u >> 16) & 1u);
    return (short)(r >> 16);
}

// ---------------- rs[j] = sum_k mlp_w[j][k] ----------------
__global__ void rowsum_k(const float* __restrict__ mw, float* __restrict__ rs) {
    int j = blockIdx.x;
    const float* row = mw + (size_t)j * HWD;
    float s = 0.f;
    for (int k = threadIdx.x; k < HWD; k += 256) s += row[k];
    __shared__ float red[256];
    red[threadIdx.x] = s; __syncthreads();
    for (int off = 128; off > 0; off >>= 1) {
        if (threadIdx.x < off) red[threadIdx.x] += red[threadIdx.x + off];
        __syncthreads();
    }
    if (threadIdx.x == 0) rs[j] = red[0];
}

// ---------------- imgs = x * sigmoid((t/20)*rs + mlp_b) ----------------
__global__ void imgs_k(const float* __restrict__ x, const float* __restrict__ rs,
                       const float* __restrict__ mb, float* __restrict__ imgs) {
    int idx = blockIdx.x * 256 + threadIdx.x;
    if (idx >= NF * HWD) return;
    int t = idx / HWD, p = idx % HWD;
    float pe = sigm(((float)t / 20.0f) * rs[p] + mb[p]);
    imgs[idx] = x[idx] * pe;
}

// ---------------- weight pack: 14 tensors -> bf16 MFMA B-fragments ----------------
// t: 0=off1_w(18) 1=off2_w(18) 2..6=rb_w1[l](32) 7..11=rb_w2[l](32) 12=dw1(32) 13=dw2(32)
__global__ void pack_k(const float* __restrict__ off1_w, const float* __restrict__ off2_w,
                       const float* __restrict__ rb_w1, const float* __restrict__ rb_w2,
                       const float* __restrict__ dw1, const float* __restrict__ dw2,
                       unsigned short* __restrict__ wp) {
    int tid = blockIdx.x * 256 + threadIdx.x;
    if (tid >= 14 * 9216) return;
    int t = tid / 9216, u = tid - t * 9216;
    int j = u & 7, l = (u >> 3) & 63, h = (u >> 9) & 1, k = u >> 10;
    int o = h * 16 + (l & 15);
    int c = 8 * (l >> 4) + j;
    const float* src;
    int cout;
    if (t == 0)       { src = off1_w; cout = 18; }
    else if (t == 1)  { src = off2_w; cout = 18; }
    else if (t < 7)   { src = rb_w1 + (size_t)(t - 2) * 9216; cout = 32; }
    else if (t < 12)  { src = rb_w2 + (size_t)(t - 7) * 9216; cout = 32; }
    else if (t == 12) { src = dw1; cout = 32; }
    else              { src = dw2; cout = 32; }
    float val = (o < cout) ? src[(o * 32 + c) * 9 + k] : 0.f;
    wp[tid] = (unsigned short)f2b(val);
}

// ---------------- MFMA 3x3 conv, 32-in NHWC fp32, COUT out ----------------
template <int COUT, bool RELU, bool HAS_RES>
__global__ __launch_bounds__(256, 1)
void mfmaconv_k(const float* __restrict__ in, const unsigned short* __restrict__ wp,
                const float* __restrict__ bias, const float* __restrict__ res,
                float* __restrict__ out, int out_ps, int Npix) {
    int lane = threadIdx.x & 63;
    int wav  = threadIdx.x >> 6;
    int pix0 = (blockIdx.x * 4 + wav) * 16;
    if (pix0 >= Npix) return;
    s16x8 bf[18];
#pragma unroll
    for (int i = 0; i < 18; ++i)
        bf[i] = *(const s16x8*)(wp + ((size_t)(i * 64 + lane)) * 8);
    int am = lane & 15;
    int ak = lane >> 4;
    int apix = pix0 + am;
    bool aval = apix < Npix;
    int ap = apix % HWD;
    int ah = ap / WD, aq = ap - ah * WD;
    const float* abase = in + (size_t)apix * 32 + ak * 8;
    f32x4 acc0 = {0.f, 0.f, 0.f, 0.f};
    f32x4 acc1 = {0.f, 0.f, 0.f, 0.f};
#pragma unroll
    for (int k = 0; k < 9; ++k) {
        int dy = k / 3 - 1, dx = k % 3 - 1;
        int hh = ah + dy, qq = aq + dx;
        bool v = aval && hh >= 0 && hh < WD && qq >= 0 && qq < WD;
        s16x8 af = {0, 0, 0, 0, 0, 0, 0, 0};
        if (v) {
            const float* ipp = abase + (dy * WD + dx) * 32;
            float4 u0 = *(const float4*)(ipp);
            float4 u1 = *(const float4*)(ipp + 4);
            af[0] = f2b(u0.x); af[1] = f2b(u0.y); af[2] = f2b(u0.z); af[3] = f2b(u0.w);
            af[4] = f2b(u1.x); af[5] = f2b(u1.y); af[6] = f2b(u1.z); af[7] = f2b(u1.w);
        }
        acc0 = __builtin_amdgcn_mfma_f32_16x16x32_bf16(af, bf[k * 2 + 0], acc0, 0, 0, 0);
        acc1 = __builtin_amdgcn_mfma_f32_16x16x32_bf16(af, bf[k * 2 + 1], acc1, 0, 0, 0);
    }
    int n = lane & 15;
    int mrow = (lane >> 4) * 4;
    float b0 = bias[n];
    float b1 = (16 + n < COUT) ? bias[16 + n] : 0.f;
#pragma unroll
    for (int i = 0; i < 4; ++i) {
        int pix = pix0 + mrow + i;
        if (pix >= Npix) continue;
        float v0 = acc0[i] + b0;
        if (RELU) v0 = fmaxf(v0, 0.f);
        if (HAS_RES) v0 += res[(size_t)pix * 32 + n];
        out[(size_t)pix * out_ps + n] = v0;
        if (16 + n < COUT) {
            float v1 = acc1[i] + b1;
            if (RELU) v1 = fmaxf(v1, 0.f);
            if (HAS_RES) v1 += res[(size_t)pix * 32 + 16 + n];
            out[(size_t)pix * out_ps + 16 + n] = v1;
        }
    }
}

// ---------------- MFMA deformable conv 3x3, 32->32, NHWC ----------------
__global__ __launch_bounds__(256, 1)
void deform_mfma_k(const float* __restrict__ base_, const float* __restrict__ off,
                   const unsigned short* __restrict__ wp, float* __restrict__ out,
                   int4 froff, int Npix) {
    int lane = threadIdx.x & 63;
    int wav  = threadIdx.x >> 6;
    int pix0 = (blockIdx.x * 4 + wav) * 16;
    if (pix0 >= Npix) return;
    s16x8 bf[18];
#pragma unroll
    for (int i = 0; i < 18; ++i)
        bf[i] = *(const s16x8*)(wp + ((size_t)(i * 64 + lane)) * 8);
    int am = lane & 15;
    int kg = lane >> 4;
    int pixel = min(pix0 + am, Npix - 1);        // clamp: invalid rows never stored
    int bi = pixel / (NJ * HWD);
    int rem = pixel - bi * (NJ * HWD);
    int n = rem / HWD, p = rem - n * HWD;
    int h = p / WD, q = p - h * WD;
    const float* xf = base_ + (size_t)(n + sel4(froff, bi)) * HWD * CC + kg * 8;
    const float* ofp = off + (size_t)pixel * 18;
    f32x4 acc0 = {0.f, 0.f, 0.f, 0.f};
    f32x4 acc1 = {0.f, 0.f, 0.f, 0.f};
#pragma unroll
    for (int kk = 0; kk < 9; ++kk) {
        int ky = kk / 3, kx = kk - ky * 3;
        float2 d = *(const float2*)(ofp + 2 * kk);
        float py = (float)(h - 1 + ky) + d.x;
        float px = (float)(q - 1 + kx) + d.y;
        float y0f = floorf(py), x0f = floorf(px);
        float ly = py - y0f, lx = px - x0f;
        int y0 = (int)y0f, x0 = (int)x0f;
        float w00 = (1.f - ly) * (1.f - lx), w01 = (1.f - ly) * lx;
        float w10 = ly * (1.f - lx), w11 = ly * lx;
        bool yv0 = (y0 >= 0 && y0 < WD), yv1 = (y0 + 1 >= 0 && y0 + 1 < WD);
        bool xv0 = (x0 >= 0 && x0 < WD), xv1 = (x0 + 1 >= 0 && x0 + 1 < WD);
        if (!(yv0 && xv0)) w00 = 0.f;
        if (!(yv0 && xv1)) w01 = 0.f;
        if (!(yv1 && xv0)) w10 = 0.f;
        if (!(yv1 && xv1)) w11 = 0.f;
        int yc0 = min(max(y0, 0), WD - 1), yc1 = min(max(y0 + 1, 0), WD - 1);
        int xc0 = min(max(x0, 0), WD - 1), xc1 = min(max(x0 + 1, 0), WD - 1);
        const float* p00 = xf + (yc0 * WD + xc0) * CC;
        const float* p01 = xf + (yc0 * WD + xc1) * CC;
        const float* p10 = xf + (yc1 * WD + xc0) * CC;
        const float* p11 = xf + (yc1 * WD + xc1) * CC;
        float4 a0 = *(const float4*)(p00);
        float4 a1 = *(const float4*)(p00 + 4);
        float4 b0 = *(const float4*)(p01);
        float4 b1 = *(const float4*)(p01 + 4);
        float4 c0 = *(const float4*)(p10);
        float4 c1 = *(const float4*)(p10 + 4);
        float4 d0 = *(const float4*)(p11);
        float4 d1 = *(const float4*)(p11 + 4);
        s16x8 af;
        af[0] = f2b(a0.x * w00 + b0.x * w01 + c0.x * w10 + d0.x * w11);
        af[1] = f2b(a0.y * w00 + b0.y * w01 + c0.y * w10 + d0.y * w11);
        af[2] = f2b(a0.z * w00 + b0.z * w01 + c0.z * w10 + d0.z * w11);
        af[3] = f2b(a0.w * w00 + b0.w * w01 + c0.w * w10 + d0.w * w11);
        af[4] = f2b(a1.x * w00 + b1.x * w01 + c1.x * w10 + d1.x * w11);
        af[5] = f2b(a1.y * w00 + b1.y * w01 + c1.y * w10 + d1.y * w11);
        af[6] = f2b(a1.z * w00 + b1.z * w01 + c1.z * w10 + d1.z * w11);
        af[7] = f2b(a1.w * w00 + b1.w * w01 + c1.w * w10 + d1.w * w11);
        acc0 = __builtin_amdgcn_mfma_f32_16x16x32_bf16(af, bf[kk * 2 + 0], acc0, 0, 0, 0);
        acc1 = __builtin_amdgcn_mfma_f32_16x16x32_bf16(af, bf[kk * 2 + 1], acc1, 0, 0, 0);
    }
    int nn = lane & 15;
    int mrow = (lane >> 4) * 4;
#pragma unroll
    for (int i = 0; i < 4; ++i) {
        int pix = pix0 + mrow + i;
        if (pix >= Npix) continue;
        out[(size_t)pix * 32 + nn]      = acc0[i];
        out[(size_t)pix * 32 + 16 + nn] = acc1[i];
    }
}

// ---------------- 3x3 conv NHWC (1 px/thread) — tail use ----------------
template <int CIN, int COUT, bool RELU, bool HAS_B, bool HAS_RES>
__global__ __launch_bounds__(256, 2)
void conv3x3_nhwc(const float* __restrict__ in,
                  const float* __restrict__ w, const float* __restrict__ b,
                  const float* __restrict__ res, int res_ps, int res_ns,
                  float* __restrict__ out, int out_ps, int out_ns, int N) {
    constexpr int WROW = (COUT + 3) & ~3;
    __shared__ float wl[9 * CIN * WROW];
    for (int i = threadIdx.x; i < 9 * CIN * WROW; i += 256) {
        int o = i % WROW, r = i / WROW;
        int c = r % CIN, k = r / CIN;
        wl[i] = (o < COUT) ? w[(o * CIN + c) * 9 + k] : 0.f;
    }
    __syncthreads();
    int idx = blockIdx.x * 256 + threadIdx.x;
    if (idx >= N * HWD) return;
    int n = idx / HWD, p = idx % HWD;
    int h = p / WD, q = p % WD;
    float acc[COUT];
#pragma unroll
    for (int o = 0; o < COUT; ++o) acc[o] = HAS_B ? b[o] : 0.f;
    const float* inn = in + (size_t)n * HWD * CIN;
#pragma unroll
    for (int k = 0; k < 9; ++k) {
        int hh = h + k / 3 - 1, qq = q + k % 3 - 1;
        if (hh < 0 || hh >= WD || qq < 0 || qq >= WD) continue;
        const float* ip = inn + (hh * WD + qq) * CIN;
        const float* wk = &wl[k * CIN * WROW];
#pragma unroll
        for (int cg = 0; cg < CIN / 4; ++cg) {
            float4 v = *(const float4*)(ip + cg * 4);
            const float* w0 = wk + (cg * 4) * WROW;
#pragma unroll
            for (int o = 0; o < COUT; ++o)
                acc[o] += v.x * w0[o] + v.y * w0[WROW + o]
                        + v.z * w0[2 * WROW + o] + v.w * w0[3 * WROW + o];
        }
    }
#pragma unroll
    for (int o = 0; o < COUT; ++o) {
        float val = acc[o];
        if (RELU) val = fmaxf(val, 0.f);
        if (HAS_RES) val += res[(size_t)n * res_ns + (size_t)p * res_ps + o];
        out[(size_t)n * out_ns + (size_t)p * out_ps + o] = val;
    }
}

// ---------------- 3x3 conv, CHW input (fe 1->32, tc0 5->32), NHWC out ----------------
template <int CIN, int COUT, bool RELU>
__global__ __launch_bounds__(256, 2)
void conv3x3_chwin(const float* __restrict__ in, int in_ns,
                   const float* __restrict__ w, const float* __restrict__ b,
                   float* __restrict__ out, int N) {
    __shared__ float wl[CIN * 9 * COUT];
    for (int i = threadIdx.x; i < CIN * 9 * COUT; i += 256) {
        int o = i % COUT, r = i / COUT;
        int k = r % 9, c = r / 9;
        wl[i] = w[(o * CIN + c) * 9 + k];
    }
    __syncthreads();
    int idx = blockIdx.x * 256 + threadIdx.x;
    if (idx >= N * HWD) return;
    int n = idx / HWD, p = idx % HWD;
    int h = p / WD, q = p % WD;
    float acc[COUT];
#pragma unroll
    for (int o = 0; o < COUT; ++o) acc[o] = b[o];
    const float* inn = in + (size_t)n * in_ns;
#pragma unroll
    for (int c = 0; c < CIN; ++c) {
#pragma unroll
        for (int k = 0; k < 9; ++k) {
            int hh = h + k / 3 - 1, qq = q + k % 3 - 1;
            if (hh < 0 || hh >= WD || qq < 0 || qq >= WD) continue;
            float v = inn[c * HWD + hh * WD + qq];
            const float* wp = &wl[(c * 9 + k) * COUT];
#pragma unroll
            for (int o = 0; o < COUT; ++o) acc[o] += v * wp[o];
        }
    }
    float* op = out + ((size_t)idx) * COUT;
#pragma unroll
    for (int o = 0; o < COUT; ++o) op[o] = RELU ? fmaxf(acc[o], 0.f) : acc[o];
}

// ---------------- a1c = 1x1 conv (16 out) of feats[n+2], NHWC ----------------
__global__ void a1c_k(const float* __restrict__ feats, const float* __restrict__ w,
                      const float* __restrict__ b, float* __restrict__ a1c) {
    __shared__ float wl[CC * 16];
    for (int i = threadIdx.x; i < CC * 16; i += 256) {
        int o = i % 16, c = i / 16;
        wl[i] = w[o * CC + c];
    }
    __syncthreads();
    int idx = blockIdx.x * 256 + threadIdx.x;
    if (idx >= NJ * HWD) return;
    int n = idx / HWD, p = idx % HWD;
    const float* f = feats + ((size_t)(n + 2) * HWD + p) * CC;
    float acc[16];
#pragma unroll
    for (int o = 0; o < 16; ++o) acc[o] = b[o];
#pragma unroll
    for (int cg = 0; cg < 8; ++cg) {
        float4 v = *(const float4*)(f + cg * 4);
        const float* w0 = &wl[cg * 4 * 16];
#pragma unroll
        for (int o = 0; o < 16; ++o)
            acc[o] += v.x * w0[o] + v.y * w0[16 + o] + v.z * w0[32 + o] + v.w * w0[48 + o];
    }
    float* op = a1c + (size_t)idx * 16;
#pragma unroll
    for (int o = 0; o < 16; o += 4)
        *(float4*)(op + o) = make_float4(acc[o], acc[o+1], acc[o+2], acc[o+3]);
}

// ---------------- batched: a2 (recomputed) + agg=[mean,max] ----------------
__global__ void aggb_k(const float* __restrict__ feats, const float* __restrict__ w,
                       const float* __restrict__ b, const float* __restrict__ a1c,
                       float* __restrict__ agg, int4 xoff, int N) {
    __shared__ float wl[CC * 16];
    for (int i = threadIdx.x; i < CC * 16; i += 256) {
        int o = i % 16, c = i / 16;
        wl[i] = w[o * CC + c];
    }
    __syncthreads();
    int idx = blockIdx.x * 256 + threadIdx.x;
    if (idx >= N) return;
    int bi = idx / (NJ * HWD);
    int rem = idx - bi * (NJ * HWD);
    int n = rem / HWD, p = rem % HWD;
    int xo = sel4(xoff, bi);
    const float* f = feats + ((size_t)(n + xo) * HWD + p) * CC;
    float acc[16];
#pragma unroll
    for (int o = 0; o < 16; ++o) acc[o] = b[o];
#pragma unroll
    for (int cg = 0; cg < 8; ++cg) {
        float4 v = *(const float4*)(f + cg * 4);
        const float* w0 = &wl[cg * 4 * 16];
#pragma unroll
        for (int o = 0; o < 16; ++o)
            acc[o] += v.x * w0[o] + v.y * w0[16 + o] + v.z * w0[32 + o] + v.w * w0[48 + o];
    }
    float sum = 0.f, mx = -1e30f;
    const float* ap = a1c + (size_t)rem * 16;
#pragma unroll
    for (int o = 0; o < 16; ++o) {
        float v = ap[o];
        sum += v; mx = fmaxf(mx, v);
    }
#pragma unroll
    for (int o = 0; o < 16; ++o) {
        sum += acc[o]; mx = fmaxf(mx, acc[o]);
    }
    agg[(size_t)idx * 2 + 0] = sum * (1.f / 32.f);
    agg[(size_t)idx * 2 + 1] = mx;
}

// ---------------- batched: sig from agg 3x3; fused = [a1c*g0, a2*g1] ----------------
__global__ void sigfusedb_k(const float* __restrict__ agg, const float* __restrict__ sqw,
                            const float* __restrict__ sqb, const float* __restrict__ a1c,
                            const float* __restrict__ feats, const float* __restrict__ w,
                            const float* __restrict__ b, float* __restrict__ fused,
                            int4 xoff, int N) {
    __shared__ float wl[CC * 16];
    for (int i = threadIdx.x; i < CC * 16; i += 256) {
        int o = i % 16, c = i / 16;
        wl[i] = w[o * CC + c];
    }
    __syncthreads();
    int idx = blockIdx.x * 256 + threadIdx.x;
    if (idx >= N) return;
    int bi = idx / (NJ * HWD);
    int rem = idx - bi * (NJ * HWD);
    int n = rem / HWD, p = rem % HWD;
    int h = p / WD, q = p % WD;
    float s0 = sqb[0], s1 = sqb[1];
    const float* ag = agg + (size_t)(idx - p) * 2;
#pragma unroll
    for (int k = 0; k < 9; ++k) {
        int hh = h + k / 3 - 1, qq = q + k % 3 - 1;
        if (hh < 0 || hh >= WD || qq < 0 || qq >= WD) continue;
        float2 v = *(const float2*)(ag + (hh * WD + qq) * 2);
        s0 += v.x * sqw[0 * 18 + 0 * 9 + k] + v.y * sqw[0 * 18 + 1 * 9 + k];
        s1 += v.x * sqw[1 * 18 + 0 * 9 + k] + v.y * sqw[1 * 18 + 1 * 9 + k];
    }
    float g0 = sigm(s0), g1 = sigm(s1);
    int xo = sel4(xoff, bi);
    const float* f = feats + ((size_t)(n + xo) * HWD + p) * CC;
    float acc[16];
#pragma unroll
    for (int o = 0; o < 16; ++o) acc[o] = b[o];
#pragma unroll
    for (int cg = 0; cg < 8; ++cg) {
        float4 v = *(const float4*)(f + cg * 4);
        const float* w0 = &wl[cg * 4 * 16];
#pragma unroll
        for (int o = 0; o < 16; ++o)
            acc[o] += v.x * w0[o] + v.y * w0[16 + o] + v.z * w0[32 + o] + v.w * w0[48 + o];
    }
    const float* ap = a1c + (size_t)rem * 16;
    float* fp = fused + (size_t)idx * CC;
#pragma unroll
    for (int o = 0; o < 16; ++o) fp[o] = ap[o] * g0;
#pragma unroll
    for (int o = 0; o < 16; ++o) fp[16 + o] = acc[o] * g1;
}

// ---------------- batched 3x3 conv 32->1 into aligned channels ----------------
__global__ void convoutb_k(const float* __restrict__ in, const float* __restrict__ w,
                           const float* __restrict__ b, float* __restrict__ outA,
                           int4 cidx, int N) {
    __shared__ float wl[9 * CC];
    for (int i = threadIdx.x; i < 9 * CC; i += 256) {
        int k = i / CC, c = i % CC;
        wl[i] = w[c * 9 + k];
    }
    __syncthreads();
    int idx = blockIdx.x * 256 + threadIdx.x;
    if (idx >= N) return;
    int bi = idx / (NJ * HWD);
    int rem = idx - bi * (NJ * HWD);
    int n = rem / HWD, p = rem % HWD;
    int h = p / WD, q = p % WD;
    int fr = idx / HWD;
    const float* inn = in + (size_t)fr * HWD * CC;
    float acc = b[0];
#pragma unroll
    for (int k = 0; k < 9; ++k) {
        int hh = h + k / 3 - 1, qq = q + k % 3 - 1;
        if (hh < 0 || hh >= WD || qq < 0 || qq >= WD) continue;
        const float* ip = inn + (hh * WD + qq) * CC;
        const float* wk = &wl[k * CC];
#pragma unroll
        for (int cg = 0; cg < 8; ++cg) {
            float4 v = *(const float4*)(ip + cg * 4);
            acc += v.x * wk[cg*4] + v.y * wk[cg*4+1] + v.z * wk[cg*4+2] + v.w * wk[cg*4+3];
        }
    }
    outA[((size_t)n * 5 + sel4(cidx, bi)) * HWD + p] = acc;
}

// ---------------- cen_raw into aligned ch2 + arange output ----------------
__global__ void misc_k(const float* __restrict__ imgs, float* __restrict__ out) {
    int idx = blockIdx.x * 256 + threadIdx.x;
    float* alig = out + 135036 + 124;
    if (idx < NJ * HWD) {
        int n = idx / HWD, p = idx % HWD;
        alig[((size_t)n * 5 + 2) * HWD + p] = imgs[(size_t)(n + 2) * HWD + p];
    }
    if (idx < NJ) out[135036 + idx] = (float)(idx + 2);
}

extern "C" void kernel_launch(void* const* d_in, const int* in_sizes, int n_in,
                              void* d_out, int out_size, void* d_ws, size_t ws_size,
                              hipStream_t stream) {
    const float* x      = (const float*)d_in[0];
    const float* mlp_w  = (const float*)d_in[1];
    const float* mlp_b  = (const float*)d_in[2];
    const float* fe_w   = (const float*)d_in[3];
    const float* fe_b   = (const float*)d_in[4];
    const float* c0_w   = (const float*)d_in[5];
    const float* c0_b   = (const float*)d_in[6];
    const float* c1_w   = (const float*)d_in[7];
    const float* c1_b   = (const float*)d_in[8];
    const float* sq_w   = (const float*)d_in[9];
    const float* sq_b   = (const float*)d_in[10];
    const float* off1_w = (const float*)d_in[11];
    const float* off1_b = (const float*)d_in[12];
    const float* dw1    = (const float*)d_in[13];
    const float* off2_w = (const float*)d_in[14];
    const float* off2_b = (const float*)d_in[15];
    const float* dw2    = (const float*)d_in[16];
    const float* conv_w = (const float*)d_in[17];
    const float* conv_b = (const float*)d_in[18];
    const float* tc0_w  = (const float*)d_in[19];
    const float* tc0_b  = (const float*)d_in[20];
    const float* rb_w1  = (const float*)d_in[21];
    const float* rb_b1  = (const float*)d_in[22];
    const float* rb_w2  = (const float*)d_in[23];
    const float* rb_b2  = (const float*)d_in[24];
    const float* tail_w = (const float*)d_in[25];

    const size_t FRAME = (size_t)NJ * HWD;  // 135036
    const size_t baseN = 1089 + (size_t)NF * HWD + (size_t)NF * HWD * CC + FRAME * 16;
    const size_t perB  = FRAME * 2 + FRAME * 32 + FRAME * 18 + FRAME * 32;
    int nb = 4;
    while (nb > 1 && (baseN + (size_t)nb * perB) * 4 > ws_size) nb >>= 1;

    float* ws = (float*)d_ws;
    float* rs    = ws;
    float* imgs  = rs + 1089;
    float* feats = imgs + NF * HWD;
    float* a1c   = feats + (size_t)NF * HWD * CC;
    float* agg   = a1c + FRAME * 16;
    float* fused = agg + (size_t)nb * FRAME * 2;
    float* offb  = fused + (size_t)nb * FRAME * 32;
    float* al1   = offb + (size_t)nb * FRAME * 18;
    float* al2   = fused;
    float* hbuf  = feats;
    float* tmp   = fused;
    // weight-pack region overlaps imgs (dead after misc_k); aligned
    unsigned short* wpack = (unsigned short*)(((uintptr_t)imgs + 63) & ~(uintptr_t)63);
    unsigned short* wp_off1 = wpack + 0 * 9216;
    unsigned short* wp_off2 = wpack + 1 * 9216;
    unsigned short* wp_dw1  = wpack + 12 * 9216;
    unsigned short* wp_dw2  = wpack + 13 * 9216;

    float* outF = (float*)d_out;
    float* outA = outF + 135036 + 124;

    const int GF = (NF * HWD + 255) / 256;
    const int GJ = (NJ * HWD + 255) / 256;

    rowsum_k<<<HWD, 256, 0, stream>>>(mlp_w, rs);
    imgs_k<<<GF, 256, 0, stream>>>(x, rs, mlp_b, imgs);
    conv3x3_chwin<1, 32, true><<<GF, 256, 0, stream>>>(imgs, HWD, fe_w, fe_b, feats, NF);
    misc_k<<<GJ, 256, 0, stream>>>(imgs, outF);           // last reader of imgs
    pack_k<<<(14 * 9216 + 255) / 256, 256, 0, stream>>>(off1_w, off2_w, rb_w1, rb_w2, dw1, dw2, wpack);
    a1c_k<<<GJ, 256, 0, stream>>>(feats, c0_w, c0_b, a1c);

    const int xoffs_all[4] = {0, 1, 3, 4};
    const int cidx_all[4]  = {0, 1, 3, 4};
    for (int pb = 0; pb < 4; pb += nb) {
        int4 xo = make_int4(xoffs_all[pb],
                            xoffs_all[(pb + 1) & 3],
                            xoffs_all[(pb + 2) & 3],
                            xoffs_all[(pb + 3) & 3]);
        int4 ci = make_int4(cidx_all[pb],
                            cidx_all[(pb + 1) & 3],
                            cidx_all[(pb + 2) & 3],
                            cidx_all[(pb + 3) & 3]);
        int4 f2 = make_int4(0, NJ, 2 * NJ, 3 * NJ);
        int N = nb * (int)FRAME;
        int GB = (N + 255) / 256;
        int GM = (N + 63) / 64;
        aggb_k<<<GB, 256, 0, stream>>>(feats, c1_w, c1_b, a1c, agg, xo, N);
        sigfusedb_k<<<GB, 256, 0, stream>>>(agg, sq_w, sq_b, a1c, feats, c1_w, c1_b, fused, xo, N);
        mfmaconv_k<18, false, false><<<GM, 256, 0, stream>>>(
            fused, wp_off1, off1_b, nullptr, offb, 18, N);
        deform_mfma_k<<<GM, 256, 0, stream>>>(feats, offb, wp_dw1, al1, xo, N);
        mfmaconv_k<18, false, false><<<GM, 256, 0, stream>>>(
            al1, wp_off2, off2_b, nullptr, offb, 18, N);
        deform_mfma_k<<<GM, 256, 0, stream>>>(al1, offb, wp_dw2, al2, f2, N);
        convoutb_k<<<GB, 256, 0, stream>>>(al2, conv_w, conv_b, outA, ci, N);
    }

    conv3x3_chwin<5, 32, true><<<GJ, 256, 0, stream>>>(outA, 5 * HWD, tc0_w, tc0_b, hbuf, NJ);
    const int GMF = ((int)FRAME + 63) / 64;
    for (int l = 0; l < 5; ++l) {
        mfmaconv_k<32, true, false><<<GMF, 256, 0, stream>>>(
            hbuf, wpack + (size_t)(2 + l) * 9216, rb_b1 + l * CC, nullptr, tmp, 32, (int)FRAME);
        mfmaconv_k<32, false, true><<<GMF, 256, 0, stream>>>(
            tmp, wpack + (size_t)(7 + l) * 9216, rb_b2 + l * CC, hbuf, hbuf, 32, (int)FRAME);
    }
    conv3x3_nhwc<32, 1, false, false, false><<<GJ, 256, 0, stream>>>(
        hbuf, tail_w, nullptr, nullptr, 0, 0, outF, 1, HWD, NJ);
}